// Round 14
// baseline (924.727 us; speedup 1.0000x reference)
//
#include <hip/hip_runtime.h>
#include <hip/hip_bf16.h>

// MoE: T=2048, H=2048, I=5632, E=8, top-2 renormalized.
// route -> lists -> cvt x bf16 (scratch=d_out) -> GEMM1 (x@w1^T SwiGLU -> bf16 h)
// -> memset out -> GEMM2 (h@w2^T * w, atomicAdd).
// R14: R13 tiles (256Mx128c / 256x256), 16-wave blocks (1 block/CU, reg-bound), but
// ALL staging via global_load_lds (A bf16 + B raw f32, zero staging regs), 3 LDS bufs,
// counted-vmcnt pipeline with TWO-iteration separation: STAGE(kt+2) at top; vmcnt(3)
// + raw s_barrier at bottom (drains tile kt+1, issued 2 iters ago -> wait ~free).
// No lgkm drain (compiler's MFMA waits retire ds_reads pre-barrier); NO sched_barrier
// pinning (R7/m141 lesson). B f32->bf16 converts at read (VALU fits in reclaimed stall).
// B LDS: phys slot p of row r holds logical slot p^(r&7); glds source pre-swizzled.
// Lessons: reg-staged pipelines spill (R4/R5); __syncthreads vmcnt(0) drain with 1
// block/CU is the binder (R13); XCD remaps convoy (R8/R12); occupancy capped by 64-AGPR
// acc (R10); traffic matters (R11/R13) but rate needs latency hiding.

#define TT 2048
#define HH 2048
#define II 5632
#define NE 8

using f32x4  = __attribute__((ext_vector_type(4))) float;
using bf16x8 = __attribute__((ext_vector_type(8))) short;

__device__ __forceinline__ uint32_t bfbits(float f) {
    __hip_bfloat16 h = __float2bfloat16(f);
    unsigned short u;
    __builtin_memcpy(&u, &h, 2);
    return (uint32_t)u;
}
__device__ __forceinline__ uint32_t pk2(float a, float b) {
    return bfbits(a) | (bfbits(b) << 16);
}
__device__ __forceinline__ uint4 pk8(const float4& a, const float4& b) {
    uint4 r;
    r.x = pk2(a.x, a.y); r.y = pk2(a.z, a.w);
    r.z = pk2(b.x, b.y); r.w = pk2(b.z, b.w);
    return r;
}
__device__ __forceinline__ bf16x8 cvt8(const float4& a, const float4& b) {
    uint4 t = pk8(a, b);
    return __builtin_bit_cast(bf16x8, t);
}
__device__ __forceinline__ void gl16(const void* g, void* l) {
    __builtin_amdgcn_global_load_lds(
        (const __attribute__((address_space(1))) unsigned int*)g,
        (__attribute__((address_space(3))) unsigned int*)l, 16, 0, 0);
}

#define VMW3() asm volatile("s_waitcnt vmcnt(3)" ::: "memory")
#define VMW0() asm volatile("s_waitcnt vmcnt(0)" ::: "memory")
#define BARR() __builtin_amdgcn_s_barrier()

// ---------------- x -> bf16 ----------------
__global__ void cvt_x(const float* __restrict__ x, __hip_bfloat16* __restrict__ xb) {
    const int i = (blockIdx.x * 256 + threadIdx.x) * 8;
    float4 a = *(const float4*)(x + i);
    float4 b = *(const float4*)(x + i + 4);
    *(uint4*)(xb + i) = pk8(a, b);
}

// ---------------- routing ----------------
__global__ void route_topk(const float* __restrict__ gating,
                           int* __restrict__ tk_idx, float* __restrict__ tk_w) {
    int t = blockIdx.x * 256 + threadIdx.x;
    if (t >= TT) return;
    float g[NE];
#pragma unroll
    for (int e = 0; e < NE; e++) g[e] = gating[t * NE + e];
    int i0 = 0; float b0 = g[0];
#pragma unroll
    for (int e = 1; e < NE; e++) if (g[e] > b0) { b0 = g[e]; i0 = e; }
    int i1 = (i0 == 0) ? 1 : 0; float b1 = g[i1];
#pragma unroll
    for (int e = 0; e < NE; e++) if (e != i0 && g[e] > b1) { b1 = g[e]; i1 = e; }
    float ex = expf(b1 - b0);
    float w0 = 1.f / (1.f + ex);
    float w1 = ex / (1.f + ex);
    tk_idx[2 * t] = i0; tk_idx[2 * t + 1] = i1;
    tk_w[2 * t] = w0;  tk_w[2 * t + 1] = w1;
}

__global__ void build_lists(const int* __restrict__ tk_idx, const float* __restrict__ tk_w,
                            int* __restrict__ list_tok, float* __restrict__ list_w,
                            int* __restrict__ counts) {
    const int e = blockIdx.x;
    const int tid = threadIdx.x;
    int flag[8]; float wt[8];
    int cnt = 0;
#pragma unroll
    for (int j = 0; j < 8; j++) {
        int t = tid * 8 + j;
        int f = -1;
        if (tk_idx[2 * t] == e) f = 0;
        else if (tk_idx[2 * t + 1] == e) f = 1;
        flag[j] = f;
        wt[j] = (f >= 0) ? tk_w[2 * t + f] : 0.f;
        cnt += (f >= 0) ? 1 : 0;
    }
    __shared__ int s[256];
    s[tid] = cnt;
    __syncthreads();
    for (int d = 1; d < 256; d <<= 1) {
        int v = (tid >= d) ? s[tid - d] : 0;
        __syncthreads();
        s[tid] += v;
        __syncthreads();
    }
    int pos = s[tid] - cnt;
#pragma unroll
    for (int j = 0; j < 8; j++) {
        if (flag[j] >= 0) {
            list_tok[e * TT + pos] = tid * 8 + j;
            list_w[e * TT + pos] = wt[j];
            pos++;
        }
    }
    if (tid == 255) counts[e] = s[255];
}

// ---------------- GEMM1: tile 256(M) x 128 I-cols, BK=32, 1024 thr / 16 waves ----------------
// LDS: A 16KB + B(f32, 256 wrows) 32KB per buf, x3 = 144KB. 1 block/CU.
__global__ __launch_bounds__(1024, 4) void gemm1_swiglu(
    const __hip_bfloat16* __restrict__ xb, const float* __restrict__ w1,
    const int* __restrict__ list_tok, const int* __restrict__ counts,
    __hip_bfloat16* __restrict__ hbuf) {
    const int e = blockIdx.y >> 3;
    const int mt = blockIdx.y & 7;
    const int cnt = counts[e];
    const int row0 = mt * 256;
    if (row0 >= cnt) return;
    int off = 0;
#pragma unroll
    for (int i = 0; i < NE; i++) if (i < e) off += counts[i];
    const int valid = min(256, cnt - row0);
    const int n0 = blockIdx.x * 128;
    const int tid = threadIdx.x;
    const int w = tid >> 6, l = tid & 63;   // 16 waves

    __shared__ uint4 As[3 * 1024];   // [buf][row 0..255][slot 0..3], linear, src pre-swizzled
    __shared__ uint4 Bs[3 * 2048];   // [buf][wrow 0..255][phys slot 0..7] f32; p holds logical p^(r&7)

    // A staging source (pre-swizzled for the aidx read pattern)
    const char* aSrc;
    {
        int r = w * 16 + (l >> 2);
        int t0 = list_tok[e * TT + row0 + min(r, valid - 1)];
        int s0 = (l & 3) ^ ((r >> 1) & 3);
        aSrc = (const char*)(xb + (size_t)t0 * HH + s0 * 8);
    }
    // B staging sources: thread t -> phys (r0 = t>>3, p0 = t&7) and (r0+128, p0).
    // phys p holds logical slot l0 = p0 ^ (r0&7)  (r0+128 has same low bits).
    const char *bSrc0, *bSrc1;
    {
        int r0 = tid >> 3, p0 = tid & 7;
        int l0 = p0 ^ (r0 & 7);
        const float* base = w1 + (size_t)e * (2 * II) * HH;
        bSrc0 = (const char*)(base + (size_t)(n0 + r0) * HH + l0 * 4);        // gate rows
        bSrc1 = (const char*)(base + (size_t)(II + n0 + r0) * HH + l0 * 4);   // up rows
    }
    auto STAGE = [&](int kt, int b) {
        const size_t kA = (size_t)kt * 64;    // 32 bf16
        const size_t kB = (size_t)kt * 128;   // 32 f32
        gl16(aSrc + kA, (char*)As + b * 16384 + w * 1024);
        gl16(bSrc0 + kB, (char*)Bs + b * 32768 + w * 1024);
        gl16(bSrc1 + kB, (char*)Bs + b * 32768 + 16384 + w * 1024);
    };

    // wave grid 4M x 4N; wave tile 64 rows x 32 cols (dual g,u)
    const int wm = w >> 2, wn = w & 3;
    const int l15 = l & 15, ks = l >> 4;
    int aidx[4];
#pragma unroll
    for (int m = 0; m < 4; m++) { int r = wm * 64 + m * 16 + l15; aidx[m] = r * 4 + (ks ^ ((r >> 1) & 3)); }
    int bg0[2], bg1[2], bu0[2], bu1[2];
#pragma unroll
    for (int n = 0; n < 2; n++) {
        int cg = wn * 32 + n * 16 + l15;   // gate wrow (0..127)
        int cu = cg + 128;                 // up wrow
        int x7 = cg & 7;                   // cu&7 == cg&7
        bg0[n] = cg * 8 + ((2 * ks) ^ x7);
        bg1[n] = cg * 8 + ((2 * ks + 1) ^ x7);
        bu0[n] = cu * 8 + ((2 * ks) ^ x7);
        bu1[n] = cu * 8 + ((2 * ks + 1) ^ x7);
    }

    f32x4 accg[4][2], accu[4][2];
#pragma unroll
    for (int m = 0; m < 4; m++)
#pragma unroll
        for (int n = 0; n < 2; n++) { accg[m][n] = 0; accu[m][n] = 0; }

    const int KT = HH / 32;  // 64
    STAGE(0, 0); STAGE(1, 1);
    VMW3();   // tile 0 landed (6 outstanding -> 3)
    BARR();

    for (int kt = 0; kt < KT; ++kt) {
        const int b = kt % 3;
        if (kt + 2 < KT) { int b2 = (kt + 2) % 3; STAGE(kt + 2, b2); }
        const float4* Bb = (const float4*)Bs + b * 2048;
        bf16x8 gf[2], uf[2];
#pragma unroll
        for (int n = 0; n < 2; n++) {
            gf[n] = cvt8(Bb[bg0[n]], Bb[bg1[n]]);
            uf[n] = cvt8(Bb[bu0[n]], Bb[bu1[n]]);
        }
        const uint4* Ab = As + b * 1024;
#pragma unroll
        for (int m = 0; m < 4; m++) {
            uint4 t = Ab[aidx[m]];
            bf16x8 af = __builtin_bit_cast(bf16x8, t);
#pragma unroll
            for (int n = 0; n < 2; n++) {
                accg[m][n] = __builtin_amdgcn_mfma_f32_16x16x32_bf16(af, gf[n], accg[m][n], 0, 0, 0);
                accu[m][n] = __builtin_amdgcn_mfma_f32_16x16x32_bf16(af, uf[n], accu[m][n], 0, 0, 0);
            }
        }
        if (kt + 1 < KT) {
            if (kt + 2 < KT) VMW3(); else VMW0();   // tile kt+1 landed (issued 2 iters ago)
            BARR();
        }
    }

    // epilogue: h = silu(g)*u -> bf16
#pragma unroll
    for (int m = 0; m < 4; m++) {
#pragma unroll
        for (int r = 0; r < 4; r++) {
            const int lr = wm * 64 + m * 16 + ks * 4 + r;
            if (lr < valid) {
                __hip_bfloat16* hrow = hbuf + (size_t)(off + row0 + lr) * II;
#pragma unroll
                for (int n = 0; n < 2; n++) {
                    const int col = n0 + wn * 32 + n * 16 + l15;
                    float g = accg[m][n][r], u = accu[m][n][r];
                    float h = g / (1.f + __expf(-g)) * u;
                    hrow[col] = __float2bfloat16(h);
                }
            }
        }
    }
}

// ---------------- GEMM2: tile 256(M) x 256(N), BK=32, 1024 thr / 16 waves ----------------
// LDS: A 16KB + B(f32, 256 rows) 32KB per buf, x3 = 144KB.
__global__ __launch_bounds__(1024, 4) void gemm2_scatter(
    const __hip_bfloat16* __restrict__ hbuf, const float* __restrict__ w2,
    const int* __restrict__ list_tok, const float* __restrict__ list_w,
    const int* __restrict__ counts, float* __restrict__ out) {
    const int e = blockIdx.y >> 3;
    const int mt = blockIdx.y & 7;
    const int cnt = counts[e];
    const int row0 = mt * 256;
    if (row0 >= cnt) return;
    int off = 0;
#pragma unroll
    for (int i = 0; i < NE; i++) if (i < e) off += counts[i];
    const int valid = min(256, cnt - row0);
    const int n0 = blockIdx.x * 256;
    const int tid = threadIdx.x;
    const int w = tid >> 6, l = tid & 63;

    __shared__ uint4 As[3 * 1024];
    __shared__ uint4 Bs[3 * 2048];

    const char* aSrc;
    {
        int r = w * 16 + (l >> 2);
        int s0 = (l & 3) ^ ((r >> 1) & 3);
        aSrc = (const char*)(hbuf + (size_t)(off + row0 + min(r, valid - 1)) * II + s0 * 8);
    }
    const char *bSrc0, *bSrc1;
    {
        int r0 = tid >> 3, p0 = tid & 7;
        int l0 = p0 ^ (r0 & 7);
        const float* base = w2 + (size_t)e * HH * II;
        bSrc0 = (const char*)(base + (size_t)(n0 + r0) * II + l0 * 4);
        bSrc1 = (const char*)(base + (size_t)(n0 + r0 + 128) * II + l0 * 4);
    }
    auto STAGE = [&](int kt, int b) {
        const size_t kA = (size_t)kt * 64;
        const size_t kB = (size_t)kt * 128;
        gl16(aSrc + kA, (char*)As + b * 16384 + w * 1024);
        gl16(bSrc0 + kB, (char*)Bs + b * 32768 + w * 1024);
        gl16(bSrc1 + kB, (char*)Bs + b * 32768 + 16384 + w * 1024);
    };

    // wave grid 4M x 4N; wave tile 64 x 64
    const int wm = w >> 2, wn = w & 3;
    const int l15 = l & 15, ks = l >> 4;
    int aidx[4];
#pragma unroll
    for (int m = 0; m < 4; m++) { int r = wm * 64 + m * 16 + l15; aidx[m] = r * 4 + (ks ^ ((r >> 1) & 3)); }
    int b0i[4], b1i[4];
#pragma unroll
    for (int n = 0; n < 4; n++) {
        int c = wn * 64 + n * 16 + l15;    // wrow (0..255)
        int x7 = c & 7;
        b0i[n] = c * 8 + ((2 * ks) ^ x7);
        b1i[n] = c * 8 + ((2 * ks + 1) ^ x7);
    }

    f32x4 acc[4][4];
#pragma unroll
    for (int m = 0; m < 4; m++)
#pragma unroll
        for (int n = 0; n < 4; n++) acc[m][n] = 0;

    const int KT = II / 32;  // 176
    STAGE(0, 0); STAGE(1, 1);
    VMW3();
    BARR();

    for (int kt = 0; kt < KT; ++kt) {
        const int b = kt % 3;
        if (kt + 2 < KT) { int b2 = (kt + 2) % 3; STAGE(kt + 2, b2); }
        const float4* Bb = (const float4*)Bs + b * 2048;
        bf16x8 bf[4];
#pragma unroll
        for (int n = 0; n < 4; n++) bf[n] = cvt8(Bb[b0i[n]], Bb[b1i[n]]);
        const uint4* Ab = As + b * 1024;
#pragma unroll
        for (int m = 0; m < 4; m++) {
            uint4 t = Ab[aidx[m]];
            bf16x8 af = __builtin_bit_cast(bf16x8, t);
#pragma unroll
            for (int n = 0; n < 4; n++)
                acc[m][n] = __builtin_amdgcn_mfma_f32_16x16x32_bf16(af, bf[n], acc[m][n], 0, 0, 0);
        }
        if (kt + 1 < KT) {
            if (kt + 2 < KT) VMW3(); else VMW0();
            BARR();
        }
    }

    // epilogue: scale by routing weight, scatter-add
#pragma unroll
    for (int m = 0; m < 4; m++) {
#pragma unroll
        for (int r = 0; r < 4; r++) {
            const int lr = wm * 64 + m * 16 + ks * 4 + r;
            if (lr < valid) {
                const int tok = list_tok[e * TT + row0 + lr];
                const float wt = list_w[e * TT + row0 + lr];
                float* orow = out + (size_t)tok * HH;
#pragma unroll
                for (int n = 0; n < 4; n++) {
                    const int col = n0 + wn * 64 + n * 16 + l15;
                    atomicAdd(orow + col, acc[m][n][r] * wt);
                }
            }
        }
    }
}

extern "C" void kernel_launch(void* const* d_in, const int* in_sizes, int n_in,
                              void* d_out, int out_size, void* d_ws, size_t ws_size,
                              hipStream_t stream) {
    const float* x      = (const float*)d_in[0];
    const float* gating = (const float*)d_in[1];
    const float* w1     = (const float*)d_in[2];
    const float* w2     = (const float*)d_in[3];
    float* out = (float*)d_out;
    char* ws = (char*)d_ws;

    int*   list_tok = (int*)(ws + 0);              // 64 KB
    float* list_w   = (float*)(ws + (64 << 10));   // 64 KB
    int*   counts   = (int*)(ws + (128 << 10));    // 32 B
    int*   tk_idx   = (int*)(ws + (132 << 10));    // 16 KB
    float* tk_w     = (float*)(ws + (148 << 10));  // 16 KB
    __hip_bfloat16* hbuf = (__hip_bfloat16*)(ws + (1 << 20));  // 4096 x 5632 bf16 = 46.1 MB

    // xb (bf16 x, 8.4 MB) lives in d_out until gemm1 is done; memset before gemm2.
    __hip_bfloat16* xb = (__hip_bfloat16*)d_out;

    route_topk<<<TT / 256, 256, 0, stream>>>(gating, tk_idx, tk_w);
    build_lists<<<NE, 256, 0, stream>>>(tk_idx, tk_w, list_tok, list_w, counts);
    cvt_x<<<TT * HH / (256 * 8), 256, 0, stream>>>(x, xb);
    gemm1_swiglu<<<dim3(II / 128, NE * 8), 1024, 0, stream>>>(xb, w1, list_tok, counts, hbuf);
    (void)hipMemsetAsync(d_out, 0, (size_t)TT * HH * sizeof(float), stream);
    gemm2_scatter<<<dim3(HH / 256, NE * 8), 1024, 0, stream>>>(hbuf, w2, list_tok, list_w, counts, out);
}

// Round 15
// 675.159 us; speedup vs baseline: 1.3696x; 1.3696x over previous
//
#include <hip/hip_runtime.h>
#include <hip/hip_bf16.h>

// MoE: T=2048, H=2048, I=5632, E=8, top-2 renormalized.
// route -> lists(+inverse) -> cvt x bf16 (scratch=d_out) -> GEMM1 (x@w1^T SwiGLU -> bf16 h)
// -> GEMM2 (h@w2^T -> gbuf rows, non-atomic) -> combine (out[t]=w0*g[r0]+w1*g[r1]).
// R15 = R11 gemm structure (best known: 512thr, 256-tall tiles, glds A, reg-roundtrip B,
// plain dbuf) + scatter-free epilogue: no atomics, no memset, fully deterministic.
// Lessons: reg-staged deep pipelines spill (R4/R5); counted-vmcnt pipelines null or
// conflict-bound (R6/R7/R14); XCD remaps convoy (R8/R12); occupancy not the binder
// (R10); 7 gemm1 schedules all ~440-590us -> gemm1 structure frozen at R11's.

#define TT 2048
#define HH 2048
#define II 5632
#define NE 8

using f32x4  = __attribute__((ext_vector_type(4))) float;
using bf16x8 = __attribute__((ext_vector_type(8))) short;

__device__ __forceinline__ uint32_t bfbits(float f) {
    __hip_bfloat16 h = __float2bfloat16(f);
    unsigned short u;
    __builtin_memcpy(&u, &h, 2);
    return (uint32_t)u;
}
__device__ __forceinline__ uint32_t pk2(float a, float b) {
    return bfbits(a) | (bfbits(b) << 16);
}
__device__ __forceinline__ uint4 pk8(const float4& a, const float4& b) {
    uint4 r;
    r.x = pk2(a.x, a.y); r.y = pk2(a.z, a.w);
    r.z = pk2(b.x, b.y); r.w = pk2(b.z, b.w);
    return r;
}
__device__ __forceinline__ void gl16(const void* g, void* l) {
    __builtin_amdgcn_global_load_lds(
        (const __attribute__((address_space(1))) unsigned int*)g,
        (__attribute__((address_space(3))) unsigned int*)l, 16, 0, 0);
}

// ---------------- x -> bf16 ----------------
__global__ void cvt_x(const float* __restrict__ x, __hip_bfloat16* __restrict__ xb) {
    const int i = (blockIdx.x * 256 + threadIdx.x) * 8;
    float4 a = *(const float4*)(x + i);
    float4 b = *(const float4*)(x + i + 4);
    *(uint4*)(xb + i) = pk8(a, b);
}

// ---------------- routing ----------------
__global__ void route_topk(const float* __restrict__ gating,
                           int* __restrict__ tk_idx, float* __restrict__ tk_w) {
    int t = blockIdx.x * 256 + threadIdx.x;
    if (t >= TT) return;
    float g[NE];
#pragma unroll
    for (int e = 0; e < NE; e++) g[e] = gating[t * NE + e];
    int i0 = 0; float b0 = g[0];
#pragma unroll
    for (int e = 1; e < NE; e++) if (g[e] > b0) { b0 = g[e]; i0 = e; }
    int i1 = (i0 == 0) ? 1 : 0; float b1 = g[i1];
#pragma unroll
    for (int e = 0; e < NE; e++) if (e != i0 && g[e] > b1) { b1 = g[e]; i1 = e; }
    float ex = expf(b1 - b0);
    float w0 = 1.f / (1.f + ex);
    float w1 = ex / (1.f + ex);
    tk_idx[2 * t] = i0; tk_idx[2 * t + 1] = i1;
    tk_w[2 * t] = w0;  tk_w[2 * t + 1] = w1;
}

// one block per expert: deterministic compaction; also writes inverse map
// inv[2t+slot] = e*TT + pos  (slot = which top-k slot this expert holds for token t)
__global__ void build_lists(const int* __restrict__ tk_idx, const float* __restrict__ tk_w,
                            int* __restrict__ list_tok, int* __restrict__ inv,
                            int* __restrict__ counts) {
    const int e = blockIdx.x;
    const int tid = threadIdx.x;
    int flag[8];
    int cnt = 0;
#pragma unroll
    for (int j = 0; j < 8; j++) {
        int t = tid * 8 + j;
        int f = -1;
        if (tk_idx[2 * t] == e) f = 0;
        else if (tk_idx[2 * t + 1] == e) f = 1;
        flag[j] = f;
        cnt += (f >= 0) ? 1 : 0;
    }
    __shared__ int s[256];
    s[tid] = cnt;
    __syncthreads();
    for (int d = 1; d < 256; d <<= 1) {
        int v = (tid >= d) ? s[tid - d] : 0;
        __syncthreads();
        s[tid] += v;
        __syncthreads();
    }
    int pos = s[tid] - cnt;
#pragma unroll
    for (int j = 0; j < 8; j++) {
        if (flag[j] >= 0) {
            int t = tid * 8 + j;
            list_tok[e * TT + pos] = t;
            inv[2 * t + flag[j]] = e * TT + pos;
            pos++;
        }
    }
    if (tid == 255) counts[e] = s[255];
}

// ---------------- GEMM1: tile 256(M) x 64 I-cols, BK=32, 512 thr / 8 waves ----------------
// Wave grid 4Mx2N, wave tile 64x32cols, dual acc = 16 frags = 64 AGPR.
// LDS: A 16KB x2 (glds) + B(g+u 128 rows) 8KB x2 = 48KB.
__global__ __launch_bounds__(512, 4) void gemm1_swiglu(
    const __hip_bfloat16* __restrict__ xb, const float* __restrict__ w1,
    const int* __restrict__ list_tok, const int* __restrict__ counts,
    __hip_bfloat16* __restrict__ hbuf) {
    const int e = blockIdx.y >> 3;
    const int mt = blockIdx.y & 7;
    const int cnt = counts[e];
    const int row0 = mt * 256;
    if (row0 >= cnt) return;
    int off = 0;
#pragma unroll
    for (int i = 0; i < NE; i++) if (i < e) off += counts[i];
    const int valid = min(256, cnt - row0);
    const int n0 = blockIdx.x * 64;
    const int tid = threadIdx.x;
    const int w = tid >> 6, l = tid & 63;   // 8 waves

    __shared__ uint4 As[2 * 1024];  // [buf][row 0..255][slot 0..3] linear; src pre-swizzled
    __shared__ uint4 Bs[2][512];    // [buf][row 0..127][slot] (g rows 0..63, u rows 64..127)

    // A staging: call c covers rows c*128 + w*16 + (l>>2)
    const char *aSrc0, *aSrc1;
    {
        int r0 = w * 16 + (l >> 2);
        int r1 = r0 + 128;
        int t0 = list_tok[e * TT + row0 + min(r0, valid - 1)];
        int t1 = list_tok[e * TT + row0 + min(r1, valid - 1)];
        int s0 = (l & 3) ^ ((r0 >> 1) & 3);
        int s1 = (l & 3) ^ ((r1 >> 1) & 3);
        aSrc0 = (const char*)(xb + (size_t)t0 * HH + s0 * 8);
        aSrc1 = (const char*)(xb + (size_t)t1 * HH + s1 * 8);
    }
    auto STAGEA = [&](int kt, int b) {
        char* ab = (char*)As + b * 16384 + w * 1024;
        gl16(aSrc0 + (size_t)kt * 64, ab);
        gl16(aSrc1 + (size_t)kt * 64, ab + 8192);
    };

    // B staging: thread -> row br (0..127), slot bu2 (0..3); br<64 -> g, else u
    const int br = tid >> 2, bu2 = tid & 3;
    const float* bSrc;
    {
        const float* base = w1 + (size_t)e * (2 * II) * HH;
        int r = (br < 64) ? (n0 + br) : (II + n0 + (br - 64));
        bSrc = base + (size_t)r * HH + bu2 * 8;
    }
    const int bwi = br * 4 + (bu2 ^ ((br >> 1) & 3));

    float4 rBa, rBb;
    auto LOADB = [&](int kt) {
        const int k = kt * 32;
        rBa = *(const float4*)(bSrc + k); rBb = *(const float4*)(bSrc + k + 4);
    };
    auto STOREB = [&](int b) { Bs[b][bwi] = pk8(rBa, rBb); };

    // wave grid 4M x 2N; wave tile 64 rows x 32 cols
    const int wm = w >> 1, wn = w & 1;
    const int l15 = l & 15, ks = l >> 4;
    int aidx[4], bgidx[2], buidx[2];
#pragma unroll
    for (int m = 0; m < 4; m++) { int r = wm * 64 + m * 16 + l15; aidx[m] = r * 4 + (ks ^ ((r >> 1) & 3)); }
#pragma unroll
    for (int n = 0; n < 2; n++) {
        int cg = wn * 32 + n * 16 + l15;       // g row in Bs
        int cu = cg + 64;                       // u row in Bs
        bgidx[n] = cg * 4 + (ks ^ ((cg >> 1) & 3));
        buidx[n] = cu * 4 + (ks ^ ((cu >> 1) & 3));
    }

    f32x4 accg[4][2], accu[4][2];
#pragma unroll
    for (int m = 0; m < 4; m++)
#pragma unroll
        for (int n = 0; n < 2; n++) { accg[m][n] = 0; accu[m][n] = 0; }

    STAGEA(0, 0); LOADB(0); STOREB(0);
    __syncthreads();
    const int KT = HH / 32;  // 64
#pragma unroll 2
    for (int kt = 0; kt < KT; ++kt) {
        const int cur = kt & 1;
        if (kt + 1 < KT) {
            STAGEA(kt + 1, cur ^ 1);
            LOADB(kt + 1);
        }
        bf16x8 gf[2], uf[2];
#pragma unroll
        for (int n = 0; n < 2; n++) {
            uint4 t = Bs[cur][bgidx[n]]; gf[n] = __builtin_bit_cast(bf16x8, t);
            uint4 t2 = Bs[cur][buidx[n]]; uf[n] = __builtin_bit_cast(bf16x8, t2);
        }
        const uint4* Ab = As + cur * 1024;
#pragma unroll
        for (int m = 0; m < 4; m++) {
            uint4 t = Ab[aidx[m]];
            bf16x8 af = __builtin_bit_cast(bf16x8, t);
#pragma unroll
            for (int n = 0; n < 2; n++) {
                accg[m][n] = __builtin_amdgcn_mfma_f32_16x16x32_bf16(af, gf[n], accg[m][n], 0, 0, 0);
                accu[m][n] = __builtin_amdgcn_mfma_f32_16x16x32_bf16(af, uf[n], accu[m][n], 0, 0, 0);
            }
        }
        if (kt + 1 < KT) STOREB(cur ^ 1);
        __syncthreads();
    }

    // epilogue: h = silu(g)*u -> bf16
#pragma unroll
    for (int m = 0; m < 4; m++) {
#pragma unroll
        for (int r = 0; r < 4; r++) {
            const int lr = wm * 64 + m * 16 + ks * 4 + r;
            if (lr < valid) {
                __hip_bfloat16* hrow = hbuf + (size_t)(off + row0 + lr) * II;
#pragma unroll
                for (int n = 0; n < 2; n++) {
                    const int col = n0 + wn * 32 + n * 16 + l15;
                    float g = accg[m][n][r], u = accu[m][n][r];
                    float h = g / (1.f + __expf(-g)) * u;
                    hrow[col] = __float2bfloat16(h);
                }
            }
        }
    }
}

// ---------------- GEMM2: tile 256(M) x 128(N), BK=32, 512 thr / 8 waves, NON-ATOMIC ----------------
// Wave grid 2Mx4N, wave tile 128x32, acc[8][2] = 16 frags = 64 AGPR.
// Writes raw h@w2^T rows to gbuf (f32); combine applies routing weights.
__global__ __launch_bounds__(512, 4) void gemm2_rows(
    const __hip_bfloat16* __restrict__ hbuf, const float* __restrict__ w2,
    const int* __restrict__ counts, float* __restrict__ gbuf) {
    const int e = blockIdx.y >> 3;
    const int mt = blockIdx.y & 7;
    const int cnt = counts[e];
    const int row0 = mt * 256;
    if (row0 >= cnt) return;
    int off = 0;
#pragma unroll
    for (int i = 0; i < NE; i++) if (i < e) off += counts[i];
    const int valid = min(256, cnt - row0);
    const int n0 = blockIdx.x * 128;
    const int tid = threadIdx.x;
    const int w = tid >> 6, l = tid & 63;

    __shared__ uint4 As[2 * 1024];  // 256 rows x 4 slots per buf
    __shared__ uint4 Bs[2][512];    // 128 rows x 4 slots per buf

    const char *aSrc0, *aSrc1;
    {
        int r0 = w * 16 + (l >> 2);
        int r1 = r0 + 128;
        int s0 = (l & 3) ^ ((r0 >> 1) & 3);
        int s1 = (l & 3) ^ ((r1 >> 1) & 3);
        aSrc0 = (const char*)(hbuf + (size_t)(off + row0 + min(r0, valid - 1)) * II + s0 * 8);
        aSrc1 = (const char*)(hbuf + (size_t)(off + row0 + min(r1, valid - 1)) * II + s1 * 8);
    }
    auto STAGEA = [&](int kt, int b) {
        char* ab = (char*)As + b * 16384 + w * 1024;
        gl16(aSrc0 + (size_t)kt * 64, ab);
        gl16(aSrc1 + (size_t)kt * 64, ab + 8192);
    };

    const int br = tid >> 2, bu2 = tid & 3;
    const float* bSrc = w2 + (size_t)e * HH * II + (size_t)(n0 + br) * II + bu2 * 8;
    const int bwi = br * 4 + (bu2 ^ ((br >> 1) & 3));

    float4 rBa, rBb;
    auto LOADB = [&](int kt) {
        const int k = kt * 32;
        rBa = *(const float4*)(bSrc + k); rBb = *(const float4*)(bSrc + k + 4);
    };
    auto STOREB = [&](int b) { Bs[b][bwi] = pk8(rBa, rBb); };

    // wave grid 2M x 4N; wave tile 128 rows x 32 cols
    const int wm = w >> 2, wn = w & 3;
    const int l15 = l & 15, ks = l >> 4;
    int aidx[8], bidx[2];
#pragma unroll
    for (int m = 0; m < 8; m++) { int r = wm * 128 + m * 16 + l15; aidx[m] = r * 4 + (ks ^ ((r >> 1) & 3)); }
#pragma unroll
    for (int n = 0; n < 2; n++) { int c = wn * 32 + n * 16 + l15; bidx[n] = c * 4 + (ks ^ ((c >> 1) & 3)); }

    f32x4 acc[8][2];
#pragma unroll
    for (int m = 0; m < 8; m++)
#pragma unroll
        for (int n = 0; n < 2; n++) acc[m][n] = 0;

    STAGEA(0, 0); LOADB(0); STOREB(0);
    __syncthreads();
    const int KT = II / 32;  // 176
#pragma unroll 2
    for (int kt = 0; kt < KT; ++kt) {
        const int cur = kt & 1;
        if (kt + 1 < KT) {
            STAGEA(kt + 1, cur ^ 1);
            LOADB(kt + 1);
        }
        bf16x8 bf[2];
#pragma unroll
        for (int n = 0; n < 2; n++) { uint4 t = Bs[cur][bidx[n]]; bf[n] = __builtin_bit_cast(bf16x8, t); }
        const uint4* Ab = As + cur * 1024;
#pragma unroll
        for (int m = 0; m < 8; m++) {
            uint4 t = Ab[aidx[m]];
            bf16x8 af = __builtin_bit_cast(bf16x8, t);
#pragma unroll
            for (int n = 0; n < 2; n++)
                acc[m][n] = __builtin_amdgcn_mfma_f32_16x16x32_bf16(af, bf[n], acc[m][n], 0, 0, 0);
        }
        if (kt + 1 < KT) STOREB(cur ^ 1);
        __syncthreads();
    }

    // epilogue: plain coalesced stores (each live row owned by exactly one block)
#pragma unroll
    for (int m = 0; m < 8; m++) {
#pragma unroll
        for (int r = 0; r < 4; r++) {
            const int lr = wm * 128 + m * 16 + ks * 4 + r;
            if (lr < valid) {
                float* orow = gbuf + (size_t)(off + row0 + lr) * HH;
#pragma unroll
                for (int n = 0; n < 2; n++) {
                    const int col = n0 + wn * 32 + n * 16 + l15;
                    orow[col] = acc[m][n][r];
                }
            }
        }
    }
}

// ---------------- combine: out[t] = w0*gbuf[row(t,0)] + w1*gbuf[row(t,1)] ----------------
__global__ void combine(const float* __restrict__ gbuf, const int* __restrict__ inv,
                        const float* __restrict__ tk_w, const int* __restrict__ counts,
                        float* __restrict__ out) {
    const int idx = blockIdx.x * 256 + threadIdx.x;
    const int t = idx >> 8;            // HH/8 = 256 chunks per token
    const int c = (idx & 255) * 8;
    int offs[NE];
    {
        int s = 0;
#pragma unroll
        for (int e = 0; e < NE; e++) { offs[e] = s; s += counts[e]; }
    }
    const int i0 = inv[2 * t], i1 = inv[2 * t + 1];
    const float w0 = tk_w[2 * t], w1 = tk_w[2 * t + 1];
    const float* g0 = gbuf + (size_t)(offs[i0 >> 11] + (i0 & 2047)) * HH + c;
    const float* g1 = gbuf + (size_t)(offs[i1 >> 11] + (i1 & 2047)) * HH + c;
    float4 a0 = *(const float4*)(g0);
    float4 a1 = *(const float4*)(g0 + 4);
    float4 b0 = *(const float4*)(g1);
    float4 b1 = *(const float4*)(g1 + 4);
    float4 o0, o1;
    o0.x = w0 * a0.x + w1 * b0.x; o0.y = w0 * a0.y + w1 * b0.y;
    o0.z = w0 * a0.z + w1 * b0.z; o0.w = w0 * a0.w + w1 * b0.w;
    o1.x = w0 * a1.x + w1 * b1.x; o1.y = w0 * a1.y + w1 * b1.y;
    o1.z = w0 * a1.z + w1 * b1.z; o1.w = w0 * a1.w + w1 * b1.w;
    float* op = out + (size_t)t * HH + c;
    *(float4*)(op) = o0;
    *(float4*)(op + 4) = o1;
}

extern "C" void kernel_launch(void* const* d_in, const int* in_sizes, int n_in,
                              void* d_out, int out_size, void* d_ws, size_t ws_size,
                              hipStream_t stream) {
    const float* x      = (const float*)d_in[0];
    const float* gating = (const float*)d_in[1];
    const float* w1     = (const float*)d_in[2];
    const float* w2     = (const float*)d_in[3];
    float* out = (float*)d_out;
    char* ws = (char*)d_ws;

    int*   list_tok = (int*)(ws + 0);              // 64 KB
    int*   inv      = (int*)(ws + (64 << 10));     // 16 KB
    int*   counts   = (int*)(ws + (96 << 10));     // 32 B
    int*   tk_idx   = (int*)(ws + (100 << 10));    // 16 KB
    float* tk_w     = (float*)(ws + (116 << 10));  // 16 KB
    __hip_bfloat16* hbuf = (__hip_bfloat16*)(ws + (1 << 20));        // 46.1 MB
    float* gbuf = (float*)(ws + (size_t)(64 << 20));                 // 4096 x 2048 f32 = 33.5 MB

    // xb (bf16 x, 8.4 MB) lives in d_out until gemm1 is done; combine overwrites out fully.
    __hip_bfloat16* xb = (__hip_bfloat16*)d_out;

    route_topk<<<TT / 256, 256, 0, stream>>>(gating, tk_idx, tk_w);
    build_lists<<<NE, 256, 0, stream>>>(tk_idx, tk_w, list_tok, inv, counts);
    cvt_x<<<TT * HH / (256 * 8), 256, 0, stream>>>(x, xb);
    gemm1_swiglu<<<dim3(II / 64, NE * 8), 512, 0, stream>>>(xb, w1, list_tok, counts, hbuf);
    gemm2_rows<<<dim3(HH / 128, NE * 8), 512, 0, stream>>>(hbuf, w2, counts, gbuf);
    combine<<<TT * HH / (256 * 8), 256, 0, stream>>>(gbuf, inv, tk_w, counts, out);
}

// Round 16
// 675.156 us; speedup vs baseline: 1.3696x; 1.0000x over previous
//
#include <hip/hip_runtime.h>
#include <hip/hip_bf16.h>

// MoE: T=2048, H=2048, I=5632, E=8, top-2 renormalized.
// route -> lists(+inv) -> cvt x bf16 (scratch=d_out) -> GEMM1 (x@w1^T SwiGLU -> bf16 h)
// -> GEMM2 (h@w2^T -> gbuf rows, non-atomic) -> combine (out[t]=w0*g[r0]+w1*g[r1]).
// R16 = R15 + counted-vmcnt pipeline with exact accounting, zero new regs/LDS patterns:
//   A: 3 glds buffers, staged kt+2 (2-iter flight).
//   B: same 8 regs, STOREB(kt+1) then LOADB(kt+2) (ds_write latches at issue; 1-iter flight).
//   barrier: lgkmcnt(0) + vmcnt(4) + raw s_barrier. 4 VMEM ops/iter => vmcnt(4) retires
//   all prior iters' ops (in-order retirement), keeps this iter's prefetches in flight.
// Lessons: reg-struct pipelines spill (R4/R5); new LDS swizzles conflict (R14); XCD
// remaps convoy (R8/R12); occupancy not the binder (R10); 256x64 tile is traffic-optimal
// at the 64-AGPR acc budget (R11/R13).

#define TT 2048
#define HH 2048
#define II 5632
#define NE 8

using f32x4  = __attribute__((ext_vector_type(4))) float;
using bf16x8 = __attribute__((ext_vector_type(8))) short;

__device__ __forceinline__ uint32_t bfbits(float f) {
    __hip_bfloat16 h = __float2bfloat16(f);
    unsigned short u;
    __builtin_memcpy(&u, &h, 2);
    return (uint32_t)u;
}
__device__ __forceinline__ uint32_t pk2(float a, float b) {
    return bfbits(a) | (bfbits(b) << 16);
}
__device__ __forceinline__ uint4 pk8(const float4& a, const float4& b) {
    uint4 r;
    r.x = pk2(a.x, a.y); r.y = pk2(a.z, a.w);
    r.z = pk2(b.x, b.y); r.w = pk2(b.z, b.w);
    return r;
}
__device__ __forceinline__ void gl16(const void* g, void* l) {
    __builtin_amdgcn_global_load_lds(
        (const __attribute__((address_space(1))) unsigned int*)g,
        (__attribute__((address_space(3))) unsigned int*)l, 16, 0, 0);
}

#define VMW4() asm volatile("s_waitcnt vmcnt(4)" ::: "memory")
#define VMW0() asm volatile("s_waitcnt vmcnt(0)" ::: "memory")
#define LGKM0() asm volatile("s_waitcnt lgkmcnt(0)" ::: "memory")
#define BARR() __builtin_amdgcn_s_barrier()

// ---------------- x -> bf16 ----------------
__global__ void cvt_x(const float* __restrict__ x, __hip_bfloat16* __restrict__ xb) {
    const int i = (blockIdx.x * 256 + threadIdx.x) * 8;
    float4 a = *(const float4*)(x + i);
    float4 b = *(const float4*)(x + i + 4);
    *(uint4*)(xb + i) = pk8(a, b);
}

// ---------------- routing ----------------
__global__ void route_topk(const float* __restrict__ gating,
                           int* __restrict__ tk_idx, float* __restrict__ tk_w) {
    int t = blockIdx.x * 256 + threadIdx.x;
    if (t >= TT) return;
    float g[NE];
#pragma unroll
    for (int e = 0; e < NE; e++) g[e] = gating[t * NE + e];
    int i0 = 0; float b0 = g[0];
#pragma unroll
    for (int e = 1; e < NE; e++) if (g[e] > b0) { b0 = g[e]; i0 = e; }
    int i1 = (i0 == 0) ? 1 : 0; float b1 = g[i1];
#pragma unroll
    for (int e = 0; e < NE; e++) if (e != i0 && g[e] > b1) { b1 = g[e]; i1 = e; }
    float ex = expf(b1 - b0);
    float w0 = 1.f / (1.f + ex);
    float w1 = ex / (1.f + ex);
    tk_idx[2 * t] = i0; tk_idx[2 * t + 1] = i1;
    tk_w[2 * t] = w0;  tk_w[2 * t + 1] = w1;
}

// one block per expert: deterministic compaction; inv[2t+slot] = e*TT + pos
__global__ void build_lists(const int* __restrict__ tk_idx, const float* __restrict__ tk_w,
                            int* __restrict__ list_tok, int* __restrict__ inv,
                            int* __restrict__ counts) {
    const int e = blockIdx.x;
    const int tid = threadIdx.x;
    int flag[8];
    int cnt = 0;
#pragma unroll
    for (int j = 0; j < 8; j++) {
        int t = tid * 8 + j;
        int f = -1;
        if (tk_idx[2 * t] == e) f = 0;
        else if (tk_idx[2 * t + 1] == e) f = 1;
        flag[j] = f;
        cnt += (f >= 0) ? 1 : 0;
    }
    __shared__ int s[256];
    s[tid] = cnt;
    __syncthreads();
    for (int d = 1; d < 256; d <<= 1) {
        int v = (tid >= d) ? s[tid - d] : 0;
        __syncthreads();
        s[tid] += v;
        __syncthreads();
    }
    int pos = s[tid] - cnt;
#pragma unroll
    for (int j = 0; j < 8; j++) {
        if (flag[j] >= 0) {
            int t = tid * 8 + j;
            list_tok[e * TT + pos] = t;
            inv[2 * t + flag[j]] = e * TT + pos;
            pos++;
        }
    }
    if (tid == 255) counts[e] = s[255];
}

// ---------------- GEMM1: tile 256(M) x 64 I-cols, BK=32, 512 thr / 8 waves ----------------
// LDS: A 16KB x3 (glds, kt+2 ahead) + B(g+u) 8KB x2 = 64KB -> 2 blocks/CU.
__global__ __launch_bounds__(512, 4) void gemm1_swiglu(
    const __hip_bfloat16* __restrict__ xb, const float* __restrict__ w1,
    const int* __restrict__ list_tok, const int* __restrict__ counts,
    __hip_bfloat16* __restrict__ hbuf) {
    const int e = blockIdx.y >> 3;
    const int mt = blockIdx.y & 7;
    const int cnt = counts[e];
    const int row0 = mt * 256;
    if (row0 >= cnt) return;
    int off = 0;
#pragma unroll
    for (int i = 0; i < NE; i++) if (i < e) off += counts[i];
    const int valid = min(256, cnt - row0);
    const int n0 = blockIdx.x * 64;
    const int tid = threadIdx.x;
    const int w = tid >> 6, l = tid & 63;   // 8 waves

    __shared__ uint4 As[3 * 1024];  // [buf][row 0..255][slot 0..3] linear; src pre-swizzled
    __shared__ uint4 Bs[2][512];    // [buf][row 0..127][slot] (g rows 0..63, u rows 64..127)

    // A staging: call c covers rows c*128 + w*16 + (l>>2)
    const char *aSrc0, *aSrc1;
    {
        int r0 = w * 16 + (l >> 2);
        int r1 = r0 + 128;
        int t0 = list_tok[e * TT + row0 + min(r0, valid - 1)];
        int t1 = list_tok[e * TT + row0 + min(r1, valid - 1)];
        int s0 = (l & 3) ^ ((r0 >> 1) & 3);
        int s1 = (l & 3) ^ ((r1 >> 1) & 3);
        aSrc0 = (const char*)(xb + (size_t)t0 * HH + s0 * 8);
        aSrc1 = (const char*)(xb + (size_t)t1 * HH + s1 * 8);
    }
    auto STAGEA = [&](int kt, int b) {
        char* ab = (char*)As + b * 16384 + w * 1024;
        gl16(aSrc0 + (size_t)kt * 64, ab);
        gl16(aSrc1 + (size_t)kt * 64, ab + 8192);
    };

    // B staging: thread -> row br (0..127), slot bu2 (0..3); br<64 -> g, else u
    const int br = tid >> 2, bu2 = tid & 3;
    const float* bSrc;
    {
        const float* base = w1 + (size_t)e * (2 * II) * HH;
        int r = (br < 64) ? (n0 + br) : (II + n0 + (br - 64));
        bSrc = base + (size_t)r * HH + bu2 * 8;
    }
    const int bwi = br * 4 + (bu2 ^ ((br >> 1) & 3));

    float4 rBa, rBb;
    auto LOADB = [&](int kt) {
        const int k = kt * 32;
        rBa = *(const float4*)(bSrc + k); rBb = *(const float4*)(bSrc + k + 4);
    };
    auto STOREB = [&](int b) { Bs[b][bwi] = pk8(rBa, rBb); };

    // wave grid 4M x 2N; wave tile 64 rows x 32 cols
    const int wm = w >> 1, wn = w & 1;
    const int l15 = l & 15, ks = l >> 4;
    int aidx[4], bgidx[2], buidx[2];
#pragma unroll
    for (int m = 0; m < 4; m++) { int r = wm * 64 + m * 16 + l15; aidx[m] = r * 4 + (ks ^ ((r >> 1) & 3)); }
#pragma unroll
    for (int n = 0; n < 2; n++) {
        int cg = wn * 32 + n * 16 + l15;       // g row in Bs
        int cu = cg + 64;                       // u row in Bs
        bgidx[n] = cg * 4 + (ks ^ ((cg >> 1) & 3));
        buidx[n] = cu * 4 + (ks ^ ((cu >> 1) & 3));
    }

    f32x4 accg[4][2], accu[4][2];
#pragma unroll
    for (int m = 0; m < 4; m++)
#pragma unroll
        for (int n = 0; n < 2; n++) { accg[m][n] = 0; accu[m][n] = 0; }

    const int KT = HH / 32;  // 64
    // prologue: A0,A1 staged; B0 drained into LDS; B1 in regs.
    STAGEA(0, 0); STAGEA(1, 1); LOADB(0);
    VMW0();
    STOREB(0);
    LOADB(1);
    LGKM0();
    BARR();

    int abR = 0;  // = kt % 3
    for (int kt = 0; kt < KT; ++kt) {
        const int cur = kt & 1;
        if (kt + 1 < KT) STOREB(cur ^ 1);                  // B(kt+1) regs -> LDS (latched at issue)
        if (kt + 2 < KT) {
            LOADB(kt + 2);                                  // reuse regs: B(kt+2) in flight 1 iter
            int abW = (abR == 0) ? 2 : abR - 1;             // (kt+2) % 3
            STAGEA(kt + 2, abW);                            // A(kt+2) in flight 2 iters
        }
        bf16x8 gf[2], uf[2];
#pragma unroll
        for (int n = 0; n < 2; n++) {
            uint4 t = Bs[cur][bgidx[n]]; gf[n] = __builtin_bit_cast(bf16x8, t);
            uint4 t2 = Bs[cur][buidx[n]]; uf[n] = __builtin_bit_cast(bf16x8, t2);
        }
        const uint4* Ab = As + abR * 1024;
#pragma unroll
        for (int m = 0; m < 4; m++) {
            uint4 t = Ab[aidx[m]];
            bf16x8 af = __builtin_bit_cast(bf16x8, t);
#pragma unroll
            for (int n = 0; n < 2; n++) {
                accg[m][n] = __builtin_amdgcn_mfma_f32_16x16x32_bf16(af, gf[n], accg[m][n], 0, 0, 0);
                accu[m][n] = __builtin_amdgcn_mfma_f32_16x16x32_bf16(af, uf[n], accu[m][n], 0, 0, 0);
            }
        }
        if (kt + 1 < KT) {
            LGKM0();                       // ds_writes + ds_reads retired
            if (kt + 2 < KT) VMW4(); else VMW0();   // prior iters' VMEM retired; this iter's 4 stay in flight
            BARR();
        }
        abR = (abR == 2) ? 0 : abR + 1;
    }

    // epilogue: h = silu(g)*u -> bf16
#pragma unroll
    for (int m = 0; m < 4; m++) {
#pragma unroll
        for (int r = 0; r < 4; r++) {
            const int lr = wm * 64 + m * 16 + ks * 4 + r;
            if (lr < valid) {
                __hip_bfloat16* hrow = hbuf + (size_t)(off + row0 + lr) * II;
#pragma unroll
                for (int n = 0; n < 2; n++) {
                    const int col = n0 + wn * 32 + n * 16 + l15;
                    float g = accg[m][n][r], u = accu[m][n][r];
                    float h = g / (1.f + __expf(-g)) * u;
                    hrow[col] = __float2bfloat16(h);
                }
            }
        }
    }
}

// ---------------- GEMM2: tile 256(M) x 128(N), BK=32, 512 thr / 8 waves, NON-ATOMIC ----------------
// LDS: A 16KB x3 + B 8KB x2 = 64KB. Same counted pipeline.
__global__ __launch_bounds__(512, 4) void gemm2_rows(
    const __hip_bfloat16* __restrict__ hbuf, const float* __restrict__ w2,
    const int* __restrict__ counts, float* __restrict__ gbuf) {
    const int e = blockIdx.y >> 3;
    const int mt = blockIdx.y & 7;
    const int cnt = counts[e];
    const int row0 = mt * 256;
    if (row0 >= cnt) return;
    int off = 0;
#pragma unroll
    for (int i = 0; i < NE; i++) if (i < e) off += counts[i];
    const int valid = min(256, cnt - row0);
    const int n0 = blockIdx.x * 128;
    const int tid = threadIdx.x;
    const int w = tid >> 6, l = tid & 63;

    __shared__ uint4 As[3 * 1024];
    __shared__ uint4 Bs[2][512];

    const char *aSrc0, *aSrc1;
    {
        int r0 = w * 16 + (l >> 2);
        int r1 = r0 + 128;
        int s0 = (l & 3) ^ ((r0 >> 1) & 3);
        int s1 = (l & 3) ^ ((r1 >> 1) & 3);
        aSrc0 = (const char*)(hbuf + (size_t)(off + row0 + min(r0, valid - 1)) * II + s0 * 8);
        aSrc1 = (const char*)(hbuf + (size_t)(off + row0 + min(r1, valid - 1)) * II + s1 * 8);
    }
    auto STAGEA = [&](int kt, int b) {
        char* ab = (char*)As + b * 16384 + w * 1024;
        gl16(aSrc0 + (size_t)kt * 64, ab);
        gl16(aSrc1 + (size_t)kt * 64, ab + 8192);
    };

    const int br = tid >> 2, bu2 = tid & 3;
    const float* bSrc = w2 + (size_t)e * HH * II + (size_t)(n0 + br) * II + bu2 * 8;
    const int bwi = br * 4 + (bu2 ^ ((br >> 1) & 3));

    float4 rBa, rBb;
    auto LOADB = [&](int kt) {
        const int k = kt * 32;
        rBa = *(const float4*)(bSrc + k); rBb = *(const float4*)(bSrc + k + 4);
    };
    auto STOREB = [&](int b) { Bs[b][bwi] = pk8(rBa, rBb); };

    // wave grid 2M x 4N; wave tile 128 rows x 32 cols
    const int wm = w >> 2, wn = w & 3;
    const int l15 = l & 15, ks = l >> 4;
    int aidx[8], bidx[2];
#pragma unroll
    for (int m = 0; m < 8; m++) { int r = wm * 128 + m * 16 + l15; aidx[m] = r * 4 + (ks ^ ((r >> 1) & 3)); }
#pragma unroll
    for (int n = 0; n < 2; n++) { int c = wn * 32 + n * 16 + l15; bidx[n] = c * 4 + (ks ^ ((c >> 1) & 3)); }

    f32x4 acc[8][2];
#pragma unroll
    for (int m = 0; m < 8; m++)
#pragma unroll
        for (int n = 0; n < 2; n++) acc[m][n] = 0;

    const int KT = II / 32;  // 176
    STAGEA(0, 0); STAGEA(1, 1); LOADB(0);
    VMW0();
    STOREB(0);
    LOADB(1);
    LGKM0();
    BARR();

    int abR = 0;
    for (int kt = 0; kt < KT; ++kt) {
        const int cur = kt & 1;
        if (kt + 1 < KT) STOREB(cur ^ 1);
        if (kt + 2 < KT) {
            LOADB(kt + 2);
            int abW = (abR == 0) ? 2 : abR - 1;
            STAGEA(kt + 2, abW);
        }
        bf16x8 bf[2];
#pragma unroll
        for (int n = 0; n < 2; n++) { uint4 t = Bs[cur][bidx[n]]; bf[n] = __builtin_bit_cast(bf16x8, t); }
        const uint4* Ab = As + abR * 1024;
#pragma unroll
        for (int m = 0; m < 8; m++) {
            uint4 t = Ab[aidx[m]];
            bf16x8 af = __builtin_bit_cast(bf16x8, t);
#pragma unroll
            for (int n = 0; n < 2; n++)
                acc[m][n] = __builtin_amdgcn_mfma_f32_16x16x32_bf16(af, bf[n], acc[m][n], 0, 0, 0);
        }
        if (kt + 1 < KT) {
            LGKM0();
            if (kt + 2 < KT) VMW4(); else VMW0();
            BARR();
        }
        abR = (abR == 2) ? 0 : abR + 1;
    }

    // epilogue: plain coalesced stores (each live row owned by exactly one block)
#pragma unroll
    for (int m = 0; m < 8; m++) {
#pragma unroll
        for (int r = 0; r < 4; r++) {
            const int lr = wm * 128 + m * 16 + ks * 4 + r;
            if (lr < valid) {
                float* orow = gbuf + (size_t)(off + row0 + lr) * HH;
#pragma unroll
                for (int n = 0; n < 2; n++) {
                    const int col = n0 + wn * 32 + n * 16 + l15;
                    orow[col] = acc[m][n][r];
                }
            }
        }
    }
}

// ---------------- combine: out[t] = w0*gbuf[row(t,0)] + w1*gbuf[row(t,1)] ----------------
__global__ void combine(const float* __restrict__ gbuf, const int* __restrict__ inv,
                        const float* __restrict__ tk_w, const int* __restrict__ counts,
                        float* __restrict__ out) {
    const int idx = blockIdx.x * 256 + threadIdx.x;
    const int t = idx >> 8;
    const int c = (idx & 255) * 8;
    int offs[NE];
    {
        int s = 0;
#pragma unroll
        for (int e = 0; e < NE; e++) { offs[e] = s; s += counts[e]; }
    }
    const int i0 = inv[2 * t], i1 = inv[2 * t + 1];
    const float w0 = tk_w[2 * t], w1 = tk_w[2 * t + 1];
    const float* g0 = gbuf + (size_t)(offs[i0 >> 11] + (i0 & 2047)) * HH + c;
    const float* g1 = gbuf + (size_t)(offs[i1 >> 11] + (i1 & 2047)) * HH + c;
    float4 a0 = *(const float4*)(g0);
    float4 a1 = *(const float4*)(g0 + 4);
    float4 b0 = *(const float4*)(g1);
    float4 b1 = *(const float4*)(g1 + 4);
    float4 o0, o1;
    o0.x = w0 * a0.x + w1 * b0.x; o0.y = w0 * a0.y + w1 * b0.y;
    o0.z = w0 * a0.z + w1 * b0.z; o0.w = w0 * a0.w + w1 * b0.w;
    o1.x = w0 * a1.x + w1 * b1.x; o1.y = w0 * a1.y + w1 * b1.y;
    o1.z = w0 * a1.z + w1 * b1.z; o1.w = w0 * a1.w + w1 * b1.w;
    float* op = out + (size_t)t * HH + c;
    *(float4*)(op) = o0;
    *(float4*)(op + 4) = o1;
}

extern "C" void kernel_launch(void* const* d_in, const int* in_sizes, int n_in,
                              void* d_out, int out_size, void* d_ws, size_t ws_size,
                              hipStream_t stream) {
    const float* x      = (const float*)d_in[0];
    const float* gating = (const float*)d_in[1];
    const float* w1     = (const float*)d_in[2];
    const float* w2     = (const float*)d_in[3];
    float* out = (float*)d_out;
    char* ws = (char*)d_ws;

    int*   list_tok = (int*)(ws + 0);              // 64 KB
    int*   inv      = (int*)(ws + (64 << 10));     // 16 KB
    int*   counts   = (int*)(ws + (96 << 10));     // 32 B
    int*   tk_idx   = (int*)(ws + (100 << 10));    // 16 KB
    float* tk_w     = (float*)(ws + (116 << 10));  // 16 KB
    __hip_bfloat16* hbuf = (__hip_bfloat16*)(ws + (1 << 20));        // 46.1 MB
    float* gbuf = (float*)(ws + (size_t)(64 << 20));                 // 33.5 MB

    // xb (bf16 x, 8.4 MB) lives in d_out until gemm1 is done; combine overwrites out fully.
    __hip_bfloat16* xb = (__hip_bfloat16*)d_out;

    route_topk<<<TT / 256, 256, 0, stream>>>(gating, tk_idx, tk_w);
    build_lists<<<NE, 256, 0, stream>>>(tk_idx, tk_w, list_tok, inv, counts);
    cvt_x<<<TT * HH / (256 * 8), 256, 0, stream>>>(x, xb);
    gemm1_swiglu<<<dim3(II / 64, NE * 8), 512, 0, stream>>>(xb, w1, list_tok, counts, hbuf);
    gemm2_rows<<<dim3(HH / 128, NE * 8), 512, 0, stream>>>(hbuf, w2, counts, gbuf);
    combine<<<TT * HH / (256 * 8), 256, 0, stream>>>(gbuf, inv, tk_w, counts, out);
}

// Round 17
// 672.779 us; speedup vs baseline: 1.3745x; 1.0035x over previous
//
#include <hip/hip_runtime.h>
#include <hip/hip_bf16.h>

// MoE: T=2048, H=2048, I=5632, E=8, top-2 renormalized.
// cvt x bf16 (scratch=d_out) -> fused route+lists(+inv) -> GEMM1 (x@w1^T SwiGLU -> bf16 h)
// -> GEMM2 (h@w2^T -> gbuf rows, non-atomic) -> combine (out[t]=w0*g[r0]+w1*g[r1]).
// R17 = R15 frozen GEMMs + fused routing (one kernel, 8 blocks, each expert re-routes
// all tokens redundantly then compacts). R16's counted-vmcnt pipeline was EXACTLY
// neutral (675.156 vs 675.159) -> reverted to the simpler R15 loop.
// Final model: gemm phase is service-rate-bound (~65K concurrent B-row streams pull
// ~1.7-2.3 TB/s HBM vs 6.7 contiguous); AGPR budget (64/wave) boxes tile area/traffic;
// 8 schedules, 2 occupancies, 2 remaps, 3 tile shapes all null or negative.

#define TT 2048
#define HH 2048
#define II 5632
#define NE 8

using f32x4  = __attribute__((ext_vector_type(4))) float;
using bf16x8 = __attribute__((ext_vector_type(8))) short;

__device__ __forceinline__ uint32_t bfbits(float f) {
    __hip_bfloat16 h = __float2bfloat16(f);
    unsigned short u;
    __builtin_memcpy(&u, &h, 2);
    return (uint32_t)u;
}
__device__ __forceinline__ uint32_t pk2(float a, float b) {
    return bfbits(a) | (bfbits(b) << 16);
}
__device__ __forceinline__ uint4 pk8(const float4& a, const float4& b) {
    uint4 r;
    r.x = pk2(a.x, a.y); r.y = pk2(a.z, a.w);
    r.z = pk2(b.x, b.y); r.w = pk2(b.z, b.w);
    return r;
}
__device__ __forceinline__ void gl16(const void* g, void* l) {
    __builtin_amdgcn_global_load_lds(
        (const __attribute__((address_space(1))) unsigned int*)g,
        (__attribute__((address_space(3))) unsigned int*)l, 16, 0, 0);
}

// ---------------- x -> bf16 ----------------
__global__ void cvt_x(const float* __restrict__ x, __hip_bfloat16* __restrict__ xb) {
    const int i = (blockIdx.x * 256 + threadIdx.x) * 8;
    float4 a = *(const float4*)(x + i);
    float4 b = *(const float4*)(x + i + 4);
    *(uint4*)(xb + i) = pk8(a, b);
}

// ---------------- fused routing + per-expert list build ----------------
// 8 blocks (one per expert). Each block re-computes top-2 routing for all 2048 tokens
// (redundant, 64KB reads) and compacts its own token list. Each token's 2 weight slots
// are written by exactly the two owning expert blocks -> tk_w fully populated.
__global__ void route_build(const float* __restrict__ gating,
                            int* __restrict__ list_tok, int* __restrict__ inv,
                            float* __restrict__ tk_w, int* __restrict__ counts) {
    const int e = blockIdx.x;
    const int tid = threadIdx.x;
    int flag[8]; float wt[8];
    int cnt = 0;
#pragma unroll
    for (int j = 0; j < 8; j++) {
        int t = tid * 8 + j;
        float g[NE];
#pragma unroll
        for (int k = 0; k < NE; k++) g[k] = gating[t * NE + k];
        int i0 = 0; float b0 = g[0];
#pragma unroll
        for (int k = 1; k < NE; k++) if (g[k] > b0) { b0 = g[k]; i0 = k; }
        int i1 = (i0 == 0) ? 1 : 0; float b1 = g[i1];
#pragma unroll
        for (int k = 0; k < NE; k++) if (k != i0 && g[k] > b1) { b1 = g[k]; i1 = k; }
        float ex = __expf(b1 - b0);
        int f = -1; float wv = 0.f;
        if (i0 == e) { f = 0; wv = 1.f / (1.f + ex); }
        else if (i1 == e) { f = 1; wv = ex / (1.f + ex); }
        flag[j] = f; wt[j] = wv;
        cnt += (f >= 0) ? 1 : 0;
    }
    __shared__ int s[256];
    s[tid] = cnt;
    __syncthreads();
    for (int d = 1; d < 256; d <<= 1) {
        int v = (tid >= d) ? s[tid - d] : 0;
        __syncthreads();
        s[tid] += v;
        __syncthreads();
    }
    int pos = s[tid] - cnt;
#pragma unroll
    for (int j = 0; j < 8; j++) {
        if (flag[j] >= 0) {
            int t = tid * 8 + j;
            list_tok[e * TT + pos] = t;
            inv[2 * t + flag[j]] = e * TT + pos;
            tk_w[2 * t + flag[j]] = wt[j];
            pos++;
        }
    }
    if (tid == 255) counts[e] = s[255];
}

// ---------------- GEMM1: tile 256(M) x 64 I-cols, BK=32, 512 thr / 8 waves ----------------
// Wave grid 4Mx2N, wave tile 64x32cols, dual acc = 16 frags = 64 AGPR.
// LDS: A 16KB x2 (glds) + B(g+u 128 rows) 8KB x2 = 48KB.
__global__ __launch_bounds__(512, 4) void gemm1_swiglu(
    const __hip_bfloat16* __restrict__ xb, const float* __restrict__ w1,
    const int* __restrict__ list_tok, const int* __restrict__ counts,
    __hip_bfloat16* __restrict__ hbuf) {
    const int e = blockIdx.y >> 3;
    const int mt = blockIdx.y & 7;
    const int cnt = counts[e];
    const int row0 = mt * 256;
    if (row0 >= cnt) return;
    int off = 0;
#pragma unroll
    for (int i = 0; i < NE; i++) if (i < e) off += counts[i];
    const int valid = min(256, cnt - row0);
    const int n0 = blockIdx.x * 64;
    const int tid = threadIdx.x;
    const int w = tid >> 6, l = tid & 63;   // 8 waves

    __shared__ uint4 As[2 * 1024];  // [buf][row 0..255][slot 0..3] linear; src pre-swizzled
    __shared__ uint4 Bs[2][512];    // [buf][row 0..127][slot] (g rows 0..63, u rows 64..127)

    // A staging: call c covers rows c*128 + w*16 + (l>>2)
    const char *aSrc0, *aSrc1;
    {
        int r0 = w * 16 + (l >> 2);
        int r1 = r0 + 128;
        int t0 = list_tok[e * TT + row0 + min(r0, valid - 1)];
        int t1 = list_tok[e * TT + row0 + min(r1, valid - 1)];
        int s0 = (l & 3) ^ ((r0 >> 1) & 3);
        int s1 = (l & 3) ^ ((r1 >> 1) & 3);
        aSrc0 = (const char*)(xb + (size_t)t0 * HH + s0 * 8);
        aSrc1 = (const char*)(xb + (size_t)t1 * HH + s1 * 8);
    }
    auto STAGEA = [&](int kt, int b) {
        char* ab = (char*)As + b * 16384 + w * 1024;
        gl16(aSrc0 + (size_t)kt * 64, ab);
        gl16(aSrc1 + (size_t)kt * 64, ab + 8192);
    };

    // B staging: thread -> row br (0..127), slot bu2 (0..3); br<64 -> g, else u
    const int br = tid >> 2, bu2 = tid & 3;
    const float* bSrc;
    {
        const float* base = w1 + (size_t)e * (2 * II) * HH;
        int r = (br < 64) ? (n0 + br) : (II + n0 + (br - 64));
        bSrc = base + (size_t)r * HH + bu2 * 8;
    }
    const int bwi = br * 4 + (bu2 ^ ((br >> 1) & 3));

    float4 rBa, rBb;
    auto LOADB = [&](int kt) {
        const int k = kt * 32;
        rBa = *(const float4*)(bSrc + k); rBb = *(const float4*)(bSrc + k + 4);
    };
    auto STOREB = [&](int b) { Bs[b][bwi] = pk8(rBa, rBb); };

    // wave grid 4M x 2N; wave tile 64 rows x 32 cols
    const int wm = w >> 1, wn = w & 1;
    const int l15 = l & 15, ks = l >> 4;
    int aidx[4], bgidx[2], buidx[2];
#pragma unroll
    for (int m = 0; m < 4; m++) { int r = wm * 64 + m * 16 + l15; aidx[m] = r * 4 + (ks ^ ((r >> 1) & 3)); }
#pragma unroll
    for (int n = 0; n < 2; n++) {
        int cg = wn * 32 + n * 16 + l15;       // g row in Bs
        int cu = cg + 64;                       // u row in Bs
        bgidx[n] = cg * 4 + (ks ^ ((cg >> 1) & 3));
        buidx[n] = cu * 4 + (ks ^ ((cu >> 1) & 3));
    }

    f32x4 accg[4][2], accu[4][2];
#pragma unroll
    for (int m = 0; m < 4; m++)
#pragma unroll
        for (int n = 0; n < 2; n++) { accg[m][n] = 0; accu[m][n] = 0; }

    STAGEA(0, 0); LOADB(0); STOREB(0);
    __syncthreads();
    const int KT = HH / 32;  // 64
#pragma unroll 2
    for (int kt = 0; kt < KT; ++kt) {
        const int cur = kt & 1;
        if (kt + 1 < KT) {
            STAGEA(kt + 1, cur ^ 1);
            LOADB(kt + 1);
        }
        bf16x8 gf[2], uf[2];
#pragma unroll
        for (int n = 0; n < 2; n++) {
            uint4 t = Bs[cur][bgidx[n]]; gf[n] = __builtin_bit_cast(bf16x8, t);
            uint4 t2 = Bs[cur][buidx[n]]; uf[n] = __builtin_bit_cast(bf16x8, t2);
        }
        const uint4* Ab = As + cur * 1024;
#pragma unroll
        for (int m = 0; m < 4; m++) {
            uint4 t = Ab[aidx[m]];
            bf16x8 af = __builtin_bit_cast(bf16x8, t);
#pragma unroll
            for (int n = 0; n < 2; n++) {
                accg[m][n] = __builtin_amdgcn_mfma_f32_16x16x32_bf16(af, gf[n], accg[m][n], 0, 0, 0);
                accu[m][n] = __builtin_amdgcn_mfma_f32_16x16x32_bf16(af, uf[n], accu[m][n], 0, 0, 0);
            }
        }
        if (kt + 1 < KT) STOREB(cur ^ 1);
        __syncthreads();
    }

    // epilogue: h = silu(g)*u -> bf16
#pragma unroll
    for (int m = 0; m < 4; m++) {
#pragma unroll
        for (int r = 0; r < 4; r++) {
            const int lr = wm * 64 + m * 16 + ks * 4 + r;
            if (lr < valid) {
                __hip_bfloat16* hrow = hbuf + (size_t)(off + row0 + lr) * II;
#pragma unroll
                for (int n = 0; n < 2; n++) {
                    const int col = n0 + wn * 32 + n * 16 + l15;
                    float g = accg[m][n][r], u = accu[m][n][r];
                    float h = g / (1.f + __expf(-g)) * u;
                    hrow[col] = __float2bfloat16(h);
                }
            }
        }
    }
}

// ---------------- GEMM2: tile 256(M) x 128(N), BK=32, 512 thr / 8 waves, NON-ATOMIC ----------------
// Wave grid 2Mx4N, wave tile 128x32, acc[8][2] = 16 frags = 64 AGPR.
__global__ __launch_bounds__(512, 4) void gemm2_rows(
    const __hip_bfloat16* __restrict__ hbuf, const float* __restrict__ w2,
    const int* __restrict__ counts, float* __restrict__ gbuf) {
    const int e = blockIdx.y >> 3;
    const int mt = blockIdx.y & 7;
    const int cnt = counts[e];
    const int row0 = mt * 256;
    if (row0 >= cnt) return;
    int off = 0;
#pragma unroll
    for (int i = 0; i < NE; i++) if (i < e) off += counts[i];
    const int valid = min(256, cnt - row0);
    const int n0 = blockIdx.x * 128;
    const int tid = threadIdx.x;
    const int w = tid >> 6, l = tid & 63;

    __shared__ uint4 As[2 * 1024];  // 256 rows x 4 slots per buf
    __shared__ uint4 Bs[2][512];    // 128 rows x 4 slots per buf

    const char *aSrc0, *aSrc1;
    {
        int r0 = w * 16 + (l >> 2);
        int r1 = r0 + 128;
        int s0 = (l & 3) ^ ((r0 >> 1) & 3);
        int s1 = (l & 3) ^ ((r1 >> 1) & 3);
        aSrc0 = (const char*)(hbuf + (size_t)(off + row0 + min(r0, valid - 1)) * II + s0 * 8);
        aSrc1 = (const char*)(hbuf + (size_t)(off + row0 + min(r1, valid - 1)) * II + s1 * 8);
    }
    auto STAGEA = [&](int kt, int b) {
        char* ab = (char*)As + b * 16384 + w * 1024;
        gl16(aSrc0 + (size_t)kt * 64, ab);
        gl16(aSrc1 + (size_t)kt * 64, ab + 8192);
    };

    const int br = tid >> 2, bu2 = tid & 3;
    const float* bSrc = w2 + (size_t)e * HH * II + (size_t)(n0 + br) * II + bu2 * 8;
    const int bwi = br * 4 + (bu2 ^ ((br >> 1) & 3));

    float4 rBa, rBb;
    auto LOADB = [&](int kt) {
        const int k = kt * 32;
        rBa = *(const float4*)(bSrc + k); rBb = *(const float4*)(bSrc + k + 4);
    };
    auto STOREB = [&](int b) { Bs[b][bwi] = pk8(rBa, rBb); };

    // wave grid 2M x 4N; wave tile 128 rows x 32 cols
    const int wm = w >> 2, wn = w & 3;
    const int l15 = l & 15, ks = l >> 4;
    int aidx[8], bidx[2];
#pragma unroll
    for (int m = 0; m < 8; m++) { int r = wm * 128 + m * 16 + l15; aidx[m] = r * 4 + (ks ^ ((r >> 1) & 3)); }
#pragma unroll
    for (int n = 0; n < 2; n++) { int c = wn * 32 + n * 16 + l15; bidx[n] = c * 4 + (ks ^ ((c >> 1) & 3)); }

    f32x4 acc[8][2];
#pragma unroll
    for (int m = 0; m < 8; m++)
#pragma unroll
        for (int n = 0; n < 2; n++) acc[m][n] = 0;

    STAGEA(0, 0); LOADB(0); STOREB(0);
    __syncthreads();
    const int KT = II / 32;  // 176
#pragma unroll 2
    for (int kt = 0; kt < KT; ++kt) {
        const int cur = kt & 1;
        if (kt + 1 < KT) {
            STAGEA(kt + 1, cur ^ 1);
            LOADB(kt + 1);
        }
        bf16x8 bf[2];
#pragma unroll
        for (int n = 0; n < 2; n++) { uint4 t = Bs[cur][bidx[n]]; bf[n] = __builtin_bit_cast(bf16x8, t); }
        const uint4* Ab = As + cur * 1024;
#pragma unroll
        for (int m = 0; m < 8; m++) {
            uint4 t = Ab[aidx[m]];
            bf16x8 af = __builtin_bit_cast(bf16x8, t);
#pragma unroll
            for (int n = 0; n < 2; n++)
                acc[m][n] = __builtin_amdgcn_mfma_f32_16x16x32_bf16(af, bf[n], acc[m][n], 0, 0, 0);
        }
        if (kt + 1 < KT) STOREB(cur ^ 1);
        __syncthreads();
    }

    // epilogue: plain coalesced stores (each live row owned by exactly one block)
#pragma unroll
    for (int m = 0; m < 8; m++) {
#pragma unroll
        for (int r = 0; r < 4; r++) {
            const int lr = wm * 128 + m * 16 + ks * 4 + r;
            if (lr < valid) {
                float* orow = gbuf + (size_t)(off + row0 + lr) * HH;
#pragma unroll
                for (int n = 0; n < 2; n++) {
                    const int col = n0 + wn * 32 + n * 16 + l15;
                    orow[col] = acc[m][n][r];
                }
            }
        }
    }
}

// ---------------- combine: out[t] = w0*gbuf[row(t,0)] + w1*gbuf[row(t,1)] ----------------
__global__ void combine(const float* __restrict__ gbuf, const int* __restrict__ inv,
                        const float* __restrict__ tk_w, const int* __restrict__ counts,
                        float* __restrict__ out) {
    const int idx = blockIdx.x * 256 + threadIdx.x;
    const int t = idx >> 8;
    const int c = (idx & 255) * 8;
    int offs[NE];
    {
        int s = 0;
#pragma unroll
        for (int e = 0; e < NE; e++) { offs[e] = s; s += counts[e]; }
    }
    const int i0 = inv[2 * t], i1 = inv[2 * t + 1];
    const float w0 = tk_w[2 * t], w1 = tk_w[2 * t + 1];
    const float* g0 = gbuf + (size_t)(offs[i0 >> 11] + (i0 & 2047)) * HH + c;
    const float* g1 = gbuf + (size_t)(offs[i1 >> 11] + (i1 & 2047)) * HH + c;
    float4 a0 = *(const float4*)(g0);
    float4 a1 = *(const float4*)(g0 + 4);
    float4 b0 = *(const float4*)(g1);
    float4 b1 = *(const float4*)(g1 + 4);
    float4 o0, o1;
    o0.x = w0 * a0.x + w1 * b0.x; o0.y = w0 * a0.y + w1 * b0.y;
    o0.z = w0 * a0.z + w1 * b0.z; o0.w = w0 * a0.w + w1 * b0.w;
    o1.x = w0 * a1.x + w1 * b1.x; o1.y = w0 * a1.y + w1 * b1.y;
    o1.z = w0 * a1.z + w1 * b1.z; o1.w = w0 * a1.w + w1 * b1.w;
    float* op = out + (size_t)t * HH + c;
    *(float4*)(op) = o0;
    *(float4*)(op + 4) = o1;
}

extern "C" void kernel_launch(void* const* d_in, const int* in_sizes, int n_in,
                              void* d_out, int out_size, void* d_ws, size_t ws_size,
                              hipStream_t stream) {
    const float* x      = (const float*)d_in[0];
    const float* gating = (const float*)d_in[1];
    const float* w1     = (const float*)d_in[2];
    const float* w2     = (const float*)d_in[3];
    float* out = (float*)d_out;
    char* ws = (char*)d_ws;

    int*   list_tok = (int*)(ws + 0);              // 64 KB
    int*   inv      = (int*)(ws + (64 << 10));     // 16 KB
    int*   counts   = (int*)(ws + (96 << 10));     // 32 B
    float* tk_w     = (float*)(ws + (116 << 10));  // 16 KB
    __hip_bfloat16* hbuf = (__hip_bfloat16*)(ws + (1 << 20));        // 46.1 MB
    float* gbuf = (float*)(ws + (size_t)(64 << 20));                 // 33.5 MB

    // xb (bf16 x, 8.4 MB) lives in d_out until gemm1 is done; combine overwrites out fully.
    __hip_bfloat16* xb = (__hip_bfloat16*)d_out;

    cvt_x<<<TT * HH / (256 * 8), 256, 0, stream>>>(x, xb);
    route_build<<<NE, 256, 0, stream>>>(gating, list_tok, inv, tk_w, counts);
    gemm1_swiglu<<<dim3(II / 64, NE * 8), 512, 0, stream>>>(xb, w1, list_tok, counts, hbuf);
    gemm2_rows<<<dim3(HH / 128, NE * 8), 512, 0, stream>>>(hbuf, w2, counts, gbuf);
    combine<<<TT * HH / (256 * 8), 256, 0, stream>>>(gbuf, inv, tk_w, counts, out);
}